// Round 3
// baseline (1131.506 us; speedup 1.0000x reference)
//
#include <hip/hip_runtime.h>
#include <hip/hip_fp16.h>
#include <math.h>

#define N_NODES 50000
#define N_EDGES 800000
#define NB 782            // ceil(50000/64) buckets of 64 dst nodes
#define CH 4096           // edges per bucket-phase unit
#define CAP 2048          // arena slots per bucket
#define BUCKET_BLOCKS 196 // ceil(800000/4096)
#define CAST_BLOCKS 6250  // N_NODES*128/4/256
#define PREPW_BLOCKS 192  // 3 * 16384/256
#define FILL_N (NB + CAST_BLOCKS + PREPW_BLOCKS)
#define PLANE2 ((size_t)N_NODES * 64)  // fp16 elems per 64-feature plane
#define GB 782            // gemm units (64 rows each)
#define SGB 3126          // 2 * ceil(50000/32) gather units
#define G16B 3125         // 50000*16/256
#define G4B 782           // ceil(50000*4/256)
#define PERS 512          // persistent blocks: 2/CU x 256 CU, guaranteed resident

typedef _Float16 half8 __attribute__((ext_vector_type(8)));
typedef float floatx4 __attribute__((ext_vector_type(4)));
typedef unsigned uintx4 __attribute__((ext_vector_type(4)));

union LdsAll {
    struct {
        int cntA[NB]; int lofs[NB]; int gbase[NB]; int part[256];
        unsigned buf[CH];
    } bk;                      // 27.3 KB (bucket phase)
    struct { int cnt64[64]; int cur64[64]; } fl;
    float wt[16 * 132];        // gemm16 phase
};

// ---- device-scope grid barrier (sense = monotone generation) --------------
// All PERS blocks are co-resident by construction (launch_bounds(256,2)).
__device__ __forceinline__ void gbar(unsigned* bar, unsigned tg) {
    __syncthreads();
    if (threadIdx.x == 0) {
        __threadfence();  // release my phase's stores (L2 writeback)
        unsigned a = __hip_atomic_fetch_add(&bar[0], 1u, __ATOMIC_ACQ_REL,
                                            __HIP_MEMORY_SCOPE_AGENT);
        if (a == PERS - 1) {
            __hip_atomic_store(&bar[0], 0u, __ATOMIC_RELAXED,
                               __HIP_MEMORY_SCOPE_AGENT);
            __hip_atomic_store(&bar[1], tg, __ATOMIC_RELEASE,
                               __HIP_MEMORY_SCOPE_AGENT);
        } else {
            while (__hip_atomic_load(&bar[1], __ATOMIC_RELAXED,
                                     __HIP_MEMORY_SCOPE_AGENT) < tg)
                __builtin_amdgcn_s_sleep(1);
        }
        __threadfence();  // acquire other blocks' stores (L2 invalidate)
    }
    __syncthreads();
}

// ---- phase 0: LDS-staged bucket scatter into padded arena -----------------
__device__ __forceinline__ void bucket_body(LdsAll& lds, int bid,
                                            const int* __restrict__ src,
                                            const int* __restrict__ dst,
                                            int* __restrict__ gcur,
                                            unsigned* __restrict__ arena) {
    const int t = threadIdx.x;
    const int ebase = bid * CH;
    const int chunkN = min(CH, N_EDGES - ebase);
    for (int i = t; i < NB; i += 256) lds.bk.cntA[i] = 0;
    __syncthreads();
    for (int i = t; i < chunkN; i += 256)
        atomicAdd(&lds.bk.cntA[dst[ebase + i] >> 6], 1);
    __syncthreads();
    int c[4];
    int s = 0;
#pragma unroll
    for (int q = 0; q < 4; ++q) {
        int idx = t * 4 + q;
        c[q] = (idx < NB) ? lds.bk.cntA[idx] : 0;
        s += c[q];
    }
    lds.bk.part[t] = s;
    __syncthreads();
    for (int d = 1; d < 256; d <<= 1) {
        int u = (t >= d) ? lds.bk.part[t - d] : 0;
        __syncthreads();
        lds.bk.part[t] += u;
        __syncthreads();
    }
    int run = (t > 0) ? lds.bk.part[t - 1] : 0;
#pragma unroll
    for (int q = 0; q < 4; ++q) {
        int idx = t * 4 + q;
        if (idx < NB) {
            lds.bk.lofs[idx] = run;
            run += c[q];
            lds.bk.gbase[idx] = (c[q] > 0) ? atomicAdd(&gcur[idx], c[q]) : 0;
            lds.bk.cntA[idx] = 0;  // reuse as placement cursor
        }
    }
    __syncthreads();
    for (int i = t; i < chunkN; i += 256) {
        int d = dst[ebase + i];
        int sv = src[ebase + i];
        int b = d >> 6;
        int pos = atomicAdd(&lds.bk.cntA[b], 1);
        lds.bk.buf[lds.bk.lofs[b] + pos] = ((unsigned)d << 16) | (unsigned)sv;
    }
    __syncthreads();
    for (int i = t; i < chunkN; i += 256) {
        unsigned v = lds.bk.buf[i];
        int b = (int)(v >> 16) >> 6;
        int q = i - lds.bk.lofs[b];
        int p = lds.bk.gbase[b] + q;
        if (p < CAP) arena[((size_t)b << 11) + p] = v;
    }
}

// ---- phase 1: bucket finalize | x->fp16 cast | W->fp16 W^T ----------------
__device__ __forceinline__ void fill_body(
    LdsAll& lds, int bid, const unsigned* __restrict__ arena,
    const int* __restrict__ gcur, unsigned* __restrict__ packed,
    float* __restrict__ dinv, unsigned short* __restrict__ eidx,
    const float* __restrict__ x, __half* __restrict__ xh,
    const float* __restrict__ W0, const float* __restrict__ W1,
    const float* __restrict__ W2, __half* __restrict__ WT) {
    const int t = threadIdx.x;
    if (bid < NB) {
        const int b = bid;
        if (t < 64) lds.fl.cnt64[t] = 0;
        __syncthreads();
        const int seglen = min(gcur[b], CAP);
        const unsigned* seg = arena + ((size_t)b << 11);
        for (int i = t; i < seglen; i += 256)
            atomicAdd(&lds.fl.cnt64[(seg[i] >> 16) & 63], 1);
        __syncthreads();
        if (t < 64) {
            int v = lds.fl.cnt64[t];
            int p = v;
#pragma unroll
            for (int d = 1; d < 64; d <<= 1) {
                int u = __shfl_up(p, d, 64);
                if (t >= d) p += u;
            }
            int excl = p - v;
            int node = b * 64 + t;
            if (node < N_NODES) {
                packed[node] = ((unsigned)((b << 11) + excl) << 11) | (unsigned)v;
                dinv[node] = rsqrtf((float)v + 2.0f);
            }
            lds.fl.cur64[t] = excl;
        }
        __syncthreads();
        const int base = b << 11;
        for (int i = t; i < seglen; i += 256) {
            unsigned v = seg[i];
            int d = (int)(v >> 16) & 63;
            int pos = atomicAdd(&lds.fl.cur64[d], 1);
            eidx[base + pos] = (unsigned short)(v & 0xFFFFu);
        }
        __syncthreads();  // protect LDS before next stride iteration
    } else if (bid < NB + CAST_BLOCKS) {
        int i = (bid - NB) * 256 + t;
        float4 v = *(const float4*)&x[(size_t)i * 4];
        union { ushort4 u; __half h[4]; } p;
        p.h[0] = __float2half(v.x); p.h[1] = __float2half(v.y);
        p.h[2] = __float2half(v.z); p.h[3] = __float2half(v.w);
        *(ushort4*)&xh[(size_t)i * 4] = p.u;
    } else {
        int idx = bid - NB - CAST_BLOCKS;
        int which = idx >> 6;
        const float* W = (which == 0) ? W0 : (which == 1) ? W1 : W2;
        int i = (idx & 63) * 256 + t;
        int k = i >> 7, n = i & 127;
        int np = ((n & 7) << 4) + (n >> 3);
        WT[which * 128 * 128 + np * 128 + k] = __float2half(W[i]);
    }
}

// ---- gemm unit: 64 rows, Hs = fp16((Ah @ W) * dinv[row]), 2-plane ---------
__device__ __forceinline__ void gemm_body(int bid, const __half* __restrict__ Ah,
                                          const __half* __restrict__ WT,
                                          const float* __restrict__ dinv,
                                          __half* __restrict__ hs) {
    const int tid = threadIdx.x;
    const int wave = tid >> 6;
    const int lane = tid & 63;
    const int m = lane & 15;
    const int quad = lane >> 4;
    const int rowA = bid * 64 + wave * 16 + m;
    const int rA = (rowA < N_NODES) ? rowA : 0;
    const __half* arow = Ah + (size_t)rA * 128 + quad * 8;
    floatx4 acc[8] = {};
#pragma unroll
    for (int kb = 0; kb < 4; ++kb) {
        half8 af = __builtin_nontemporal_load((const half8*)(arow + kb * 32));
#pragma unroll
        for (int nt = 0; nt < 8; ++nt) {
            half8 bf = *(const half8*)(WT + (size_t)(nt * 16 + m) * 128 +
                                       kb * 32 + quad * 8);
            acc[nt] = __builtin_amdgcn_mfma_f32_16x16x32_f16(af, bf, acc[nt],
                                                             0, 0, 0);
        }
    }
    const int rb = bid * 64 + wave * 16 + quad * 4;
    __half* base = hs + (m >> 3) * PLANE2 + (m & 7) * 8;
#pragma unroll
    for (int r = 0; r < 4; ++r) {
        int row = rb + r;
        if (row < N_NODES) {
            float dv = dinv[row];
            union { uintx4 u; __half h[8]; } pk;
#pragma unroll
            for (int nt = 0; nt < 8; ++nt)
                pk.h[nt] = __float2half(acc[nt][r] * dv);
            *(uintx4*)(base + (size_t)row * 64) = pk.u;
        }
    }
}

// ---- gather unit: 32 nodes x 1 plane, 8 lanes/node ------------------------
__device__ __forceinline__ void accv(uint4 t, float* acc) {
    union { uint4 u; __half2 h2[4]; } v;
    v.u = t;
#pragma unroll
    for (int q = 0; q < 4; ++q) {
        float2 w = __half22float2(v.h2[q]);
        acc[2 * q] += w.x;
        acc[2 * q + 1] += w.y;
    }
}
__device__ __forceinline__ void store8_nt(__half* p, const float* o) {
    union { uintx4 u; __half h[8]; } c;
#pragma unroll
    for (int j = 0; j < 8; ++j) c.h[j] = __float2half(o[j]);
    __builtin_nontemporal_store(c.u, (uintx4*)p);
}

__device__ __forceinline__ void gather2_body(
    int bid, const unsigned* __restrict__ packed,
    const unsigned short* __restrict__ eidx, const __half* __restrict__ hs,
    const float* __restrict__ dinv, const float* __restrict__ bias,
    __half* __restrict__ out) {
    const int s = bid & 1;  // plane parity preserved across +=PERS strides
    const int nb = bid >> 1;
    const int t = threadIdx.x;
    const int r = nb * 32 + (t >> 3);
    if (r >= N_NODES) return;  // helper-return == skip unit (inlined)
    const int l8 = t & 7;
    const int fl = l8 * 8;
    const __half* plane = hs + s * PLANE2;
    const float dv = dinv[r];
    float bo[8];
    {
        float4 c0 = *(const float4*)&bias[s * 64 + fl];
        float4 c1 = *(const float4*)&bias[s * 64 + fl + 4];
        bo[0] = c0.x; bo[1] = c0.y; bo[2] = c0.z; bo[3] = c0.w;
        bo[4] = c1.x; bo[5] = c1.y; bo[6] = c1.z; bo[7] = c1.w;
    }
    float acc[8];
    {
        union { uint4 u; __half2 h2[4]; } p;
        p.u = *(const uint4*)&plane[(size_t)r * 64 + fl];
#pragma unroll
        for (int q = 0; q < 4; ++q) {
            float2 v = __half22float2(p.h2[q]);
            acc[2 * q] = 2.f * v.x;
            acc[2 * q + 1] = 2.f * v.y;
        }
    }
    unsigned pk = packed[r];
    int i = (int)(pk >> 11);
    int end = i + (int)(pk & 2047u);
    for (; i + 16 <= end; i += 16) {
        int mya = (int)__builtin_nontemporal_load(&eidx[i + l8]);
        int myb = (int)__builtin_nontemporal_load(&eidx[i + 8 + l8]);
        uint4 va[8], vb[8];
#pragma unroll
        for (int j = 0; j < 8; ++j) {
            int s0 = __shfl(mya, j, 8);
            va[j] = *(const uint4*)&plane[(size_t)s0 * 64 + fl];
        }
#pragma unroll
        for (int j = 0; j < 8; ++j) {
            int s0 = __shfl(myb, j, 8);
            vb[j] = *(const uint4*)&plane[(size_t)s0 * 64 + fl];
        }
#pragma unroll
        for (int j = 0; j < 8; ++j) accv(va[j], acc);
#pragma unroll
        for (int j = 0; j < 8; ++j) accv(vb[j], acc);
    }
    for (; i + 8 <= end; i += 8) {
        int mya = (int)__builtin_nontemporal_load(&eidx[i + l8]);
        uint4 va[8];
#pragma unroll
        for (int j = 0; j < 8; ++j) {
            int s0 = __shfl(mya, j, 8);
            va[j] = *(const uint4*)&plane[(size_t)s0 * 64 + fl];
        }
#pragma unroll
        for (int j = 0; j < 8; ++j) accv(va[j], acc);
    }
    if (i < end) {
        int n = end - i;
        int mya = (l8 < n) ? (int)eidx[i + l8] : 0;
        for (int j = 0; j < n; ++j) {
            int s0 = __shfl(mya, j, 8);
            accv(*(const uint4*)&plane[(size_t)s0 * 64 + fl], acc);
        }
    }
    float o[8];
#pragma unroll
    for (int j = 0; j < 8; ++j)
        o[j] = fmaxf(dv * acc[j] + bo[j], 0.f);
    store8_nt(out + (size_t)r * 128 + s * 64 + fl, o);
}

// ---- gemm16 unit (W3 preloaded in LDS by caller) --------------------------
__device__ __forceinline__ void gemm16_body(LdsAll& lds, int bid,
                                            const __half* __restrict__ in,
                                            const float* __restrict__ dinv,
                                            float* __restrict__ hs) {
    int gid = bid * 256 + threadIdx.x;  // < 800000 exactly
    int r = gid >> 4, c = gid & 15;
    const __half* arow = &in[(size_t)r * 128];
    const float* wrow = &lds.wt[c * 132];
    float acc = 0.f;
#pragma unroll
    for (int k0 = 0; k0 < 128; k0 += 8) {
        union { uint4 u; __half2 h2[4]; } p;
        p.u = *(const uint4*)&arow[k0];
#pragma unroll
        for (int q = 0; q < 4; ++q) {
            float2 a = __half22float2(p.h2[q]);
            acc += a.x * wrow[k0 + 2 * q] + a.y * wrow[k0 + 2 * q + 1];
        }
    }
    hs[gid] = acc * dinv[r];
}

// ---- gather4 unit (last layer, fp32, tanh) --------------------------------
__device__ __forceinline__ void gather4_body(
    int bid, const unsigned* __restrict__ packed,
    const unsigned short* __restrict__ eidx, const float* __restrict__ hs,
    const float* __restrict__ dinv, const float* __restrict__ bias,
    float* __restrict__ out) {
    int tid = bid * 256 + threadIdx.x;
    int r = tid >> 2;
    if (r >= N_NODES) return;
    int l = tid & 3;
    int f = l * 4;
    const float dv = dinv[r];
    const float4 bi = *(const float4*)&bias[f];
    float4 h = *(const float4*)&hs[(size_t)r * 16 + f];
    float ax = 2.f * h.x, ay = 2.f * h.y, az = 2.f * h.z, aw = 2.f * h.w;
    unsigned pk = packed[r];
    int i = (int)(pk >> 11);
    int end = i + (int)(pk & 2047u);
    for (; i + 4 <= end; i += 4) {
        int my = (int)eidx[i + l];
#pragma unroll
        for (int j = 0; j < 4; ++j) {
            int s = __shfl(my, j, 4);
            float4 v = *(const float4*)&hs[(size_t)s * 16 + f];
            ax += v.x; ay += v.y; az += v.z; aw += v.w;
        }
    }
    if (i < end) {
        int n = end - i;
        int my = (l < n) ? (int)eidx[i + l] : 0;
        for (int j = 0; j < n; ++j) {
            int s = __shfl(my, j, 4);
            float4 v = *(const float4*)&hs[(size_t)s * 16 + f];
            ax += v.x; ay += v.y; az += v.z; aw += v.w;
        }
    }
    float v0 = tanhf(dv * ax + bi.x);
    float v1 = tanhf(dv * ay + bi.y);
    float v2 = tanhf(dv * az + bi.z);
    float v3 = tanhf(dv * aw + bi.w);
    floatx4 o = {v0, v1, v2, v3};
    __builtin_nontemporal_store(o, (floatx4*)&out[(size_t)r * 16 + f]);
}

// ====== persistent mega-kernel: all 10 phases, 9 grid barriers =============
__global__ __launch_bounds__(256, 2) void k_mega(
    const int* __restrict__ src, const int* __restrict__ dst,
    const float* __restrict__ x, const float* __restrict__ W0,
    const float* __restrict__ bb0, const float* __restrict__ W1,
    const float* __restrict__ bb1, const float* __restrict__ W2,
    const float* __restrict__ bb2, const float* __restrict__ W3,
    const float* __restrict__ bb3, int* __restrict__ gcur,
    unsigned* __restrict__ arena, unsigned* __restrict__ packed,
    float* __restrict__ dinv, unsigned short* __restrict__ eidx,
    __half* __restrict__ A, __half* __restrict__ Hh,
    __half* __restrict__ WT, float* __restrict__ H16,
    float* __restrict__ out, unsigned* __restrict__ bar) {
    __shared__ LdsAll lds;
    const int b0id = blockIdx.x;
    const int t = threadIdx.x;

    // phase 0: bucket scatter (196 units)
    if (b0id < BUCKET_BLOCKS) bucket_body(lds, b0id, src, dst, gcur, arena);
    gbar(bar, 1);
    // phase 1: finalize + cast + W prep (7224 units)
    for (int bid = b0id; bid < FILL_N; bid += PERS)
        fill_body(lds, bid, arena, gcur, packed, dinv, eidx, x, A, W0, W1, W2, WT);
    gbar(bar, 2);
    // layer 0
    for (int bid = b0id; bid < GB; bid += PERS) gemm_body(bid, A, WT, dinv, Hh);
    gbar(bar, 3);
    for (int bid = b0id; bid < SGB; bid += PERS)
        gather2_body(bid, packed, eidx, Hh, dinv, bb0, A);
    gbar(bar, 4);
    // layer 1
    for (int bid = b0id; bid < GB; bid += PERS)
        gemm_body(bid, A, WT + 128 * 128, dinv, Hh);
    gbar(bar, 5);
    for (int bid = b0id; bid < SGB; bid += PERS)
        gather2_body(bid, packed, eidx, Hh, dinv, bb1, A);
    gbar(bar, 6);
    // layer 2
    for (int bid = b0id; bid < GB; bid += PERS)
        gemm_body(bid, A, WT + 2 * 128 * 128, dinv, Hh);
    gbar(bar, 7);
    for (int bid = b0id; bid < SGB; bid += PERS)
        gather2_body(bid, packed, eidx, Hh, dinv, bb2, A);
    gbar(bar, 8);
    // layer 3: 128 -> 16 dense (W3 in LDS once), then fp32 gather + tanh
    for (int i = t; i < 128 * 16; i += 256) {
        int k = i >> 4, c = i & 15;
        lds.wt[c * 132 + k] = W3[i];
    }
    __syncthreads();
    for (int bid = b0id; bid < G16B; bid += PERS)
        gemm16_body(lds, bid, A, dinv, H16);
    gbar(bar, 9);
    for (int bid = b0id; bid < G4B; bid += PERS)
        gather4_body(bid, packed, eidx, H16, dinv, bb3, out);
    // final: reset barrier so rocprof kernel-only replays stay correct
    gbar(bar, 10);
    if (b0id == 0 && t == 0) {
        __hip_atomic_store(&bar[1], 0u, __ATOMIC_RELAXED,
                           __HIP_MEMORY_SCOPE_AGENT);
    }
}

extern "C" void kernel_launch(void* const* d_in, const int* in_sizes, int n_in,
                              void* d_out, int out_size, void* d_ws, size_t ws_size,
                              hipStream_t stream) {
    const float* x  = (const float*)d_in[0];
    const int* ei   = (const int*)d_in[1];
    const float* W0 = (const float*)d_in[2];
    const float* b0 = (const float*)d_in[3];
    const float* W1 = (const float*)d_in[4];
    const float* b1 = (const float*)d_in[5];
    const float* W2 = (const float*)d_in[6];
    const float* b2 = (const float*)d_in[7];
    const float* W3 = (const float*)d_in[8];
    const float* b3 = (const float*)d_in[9];
    const int* src = ei;
    const int* dst = ei + N_EDGES;

    // ws layout (16B-aligned):
    __half* A      = (__half*)d_ws;                        // 50000*128 f16
    __half* Hh     = A + (size_t)N_NODES * 128;            // 2 planes of 64
    __half* WT     = Hh + (size_t)N_NODES * 128;           // 3*128*128 f16
    float*  H16    = (float*)(WT + 3 * 128 * 128);         // 50000*16 f32
    float*  dinv   = H16 + (size_t)N_NODES * 16;           // 50000
    unsigned* packed = (unsigned*)(dinv + N_NODES);        // 50000
    int*    gcur   = (int*)(packed + N_NODES);             // 1024 (NB=782 used)
    unsigned short* eidx = (unsigned short*)(gcur + 1024); // NB*CAP u16
    unsigned* arena = (unsigned*)(eidx + NB * CAP);        // NB*CAP
    unsigned* bar  = (unsigned*)(gcur + 1000);             // [arrive, gen] in
                                                           // gcur's zeroed pad

    (void)hipMemsetAsync(gcur, 0, 1024 * sizeof(int), stream);
    k_mega<<<PERS, 256, 0, stream>>>(src, dst, x, W0, b0, W1, b1, W2, b2, W3,
                                     b3, gcur, arena, packed, dinv, eidx, A,
                                     Hh, WT, H16, (float*)d_out, bar);
}

// Round 4
// 287.751 us; speedup vs baseline: 3.9322x; 3.9322x over previous
//
#include <hip/hip_runtime.h>
#include <hip/hip_fp16.h>
#include <math.h>

#define N_NODES 50000
#define N_EDGES 800000
#define NB 782            // ceil(50000/64) buckets of 64 dst nodes
#define CH 4096           // edges per k_bucket block
#define CAP 2048          // arena slots per bucket (Poisson(1024) -> 2x slack)
#define BUCKET_BLOCKS 196 // ceil(800000/4096)
#define CAST_BLOCKS 6250  // N_NODES*128/4/256
#define PREPW_BLOCKS 192  // 3 * 16384/256
#define FILL_GRID (NB + CAST_BLOCKS + PREPW_BLOCKS)
#define FB 1563           // ceil(50000/32) fused-layer blocks (32 nodes each)

typedef _Float16 half8 __attribute__((ext_vector_type(8)));
typedef float floatx4 __attribute__((ext_vector_type(4)));
typedef unsigned uintx4 __attribute__((ext_vector_type(4)));

// ---- pass 1: LDS-staged bucket scatter into padded arena ------------------
__global__ __launch_bounds__(256) void k_bucket(const int* __restrict__ src,
                                                const int* __restrict__ dst,
                                                int* __restrict__ gcur,
                                                unsigned* __restrict__ arena) {
    __shared__ int cntA[NB];
    __shared__ int lofs[NB];
    __shared__ int gbase[NB];
    __shared__ int part[256];
    __shared__ unsigned buf[CH];
    const int t = threadIdx.x;
    const int ebase = blockIdx.x * CH;
    const int chunkN = min(CH, N_EDGES - ebase);

    for (int i = t; i < NB; i += 256) cntA[i] = 0;
    __syncthreads();
    for (int i = t; i < chunkN; i += 256)
        atomicAdd(&cntA[dst[ebase + i] >> 6], 1);
    __syncthreads();
    int c[4];
    int s = 0;
#pragma unroll
    for (int q = 0; q < 4; ++q) {
        int idx = t * 4 + q;
        c[q] = (idx < NB) ? cntA[idx] : 0;
        s += c[q];
    }
    part[t] = s;
    __syncthreads();
    for (int d = 1; d < 256; d <<= 1) {
        int u = (t >= d) ? part[t - d] : 0;
        __syncthreads();
        part[t] += u;
        __syncthreads();
    }
    int run = (t > 0) ? part[t - 1] : 0;
#pragma unroll
    for (int q = 0; q < 4; ++q) {
        int idx = t * 4 + q;
        if (idx < NB) {
            lofs[idx] = run;
            run += c[q];
            gbase[idx] = (c[q] > 0) ? atomicAdd(&gcur[idx], c[q]) : 0;
            cntA[idx] = 0;  // reuse as placement cursor
        }
    }
    __syncthreads();
    for (int i = t; i < chunkN; i += 256) {
        int d = dst[ebase + i];
        int sv = src[ebase + i];
        int b = d >> 6;
        int pos = atomicAdd(&cntA[b], 1);
        buf[lofs[b] + pos] = ((unsigned)d << 16) | (unsigned)sv;
    }
    __syncthreads();
    for (int i = t; i < chunkN; i += 256) {
        unsigned v = buf[i];
        int b = (int)(v >> 16) >> 6;
        int q = i - lofs[b];
        int p = gbase[b] + q;
        if (p < CAP) arena[((size_t)b << 11) + p] = v;
    }
}

// ---- pass 2 (fused): bucket finalize | x->fp16 cast | W->fp16 W^T ---------
__global__ __launch_bounds__(256) void k_fill3prep(
    const unsigned* __restrict__ arena, const int* __restrict__ gcur,
    unsigned* __restrict__ packed, float* __restrict__ dinv,
    unsigned short* __restrict__ eidx, const float* __restrict__ x,
    __half* __restrict__ xh, const float* __restrict__ W0,
    const float* __restrict__ W1, const float* __restrict__ W2,
    __half* __restrict__ WT) {
    const int t = threadIdx.x;
    if (blockIdx.x < NB) {
        const int b = blockIdx.x;
        __shared__ int cnt64[64];
        __shared__ int cur64[64];
        if (t < 64) cnt64[t] = 0;
        __syncthreads();
        const int seglen = min(gcur[b], CAP);
        const unsigned* seg = arena + ((size_t)b << 11);
        for (int i = t; i < seglen; i += 256)
            atomicAdd(&cnt64[(seg[i] >> 16) & 63], 1);
        __syncthreads();
        if (t < 64) {  // one wave: prefix scan of 64 counts
            int v = cnt64[t];
            int p = v;
#pragma unroll
            for (int d = 1; d < 64; d <<= 1) {
                int u = __shfl_up(p, d, 64);
                if (t >= d) p += u;
            }
            int excl = p - v;
            int node = b * 64 + t;
            if (node < N_NODES) {
                packed[node] =
                    ((unsigned)((b << 11) + excl) << 11) | (unsigned)v;
                dinv[node] = rsqrtf((float)v + 2.0f);  // improved: +2
            }
            cur64[t] = excl;
        }
        __syncthreads();
        const int base = b << 11;
        for (int i = t; i < seglen; i += 256) {
            unsigned v = seg[i];
            int d = (int)(v >> 16) & 63;
            int pos = atomicAdd(&cur64[d], 1);
            eidx[base + pos] = (unsigned short)(v & 0xFFFFu);
        }
    } else if (blockIdx.x < NB + CAST_BLOCKS) {
        int i = (blockIdx.x - NB) * 256 + t;  // float4-granular, exact
        float4 v = *(const float4*)&x[(size_t)i * 4];
        union { ushort4 u; __half h[4]; } p;
        p.h[0] = __float2half(v.x); p.h[1] = __float2half(v.y);
        p.h[2] = __float2half(v.z); p.h[3] = __float2half(v.w);
        *(ushort4*)&xh[(size_t)i * 4] = p.u;
    } else {
        int idx = blockIdx.x - NB - CAST_BLOCKS;  // 0..191
        int which = idx >> 6;
        const float* W = (which == 0) ? W0 : (which == 1) ? W1 : W2;
        int i = (idx & 63) * 256 + t;  // 16384 per matrix: i = k*128 + n
        int k = i >> 7, n = i & 127;
        int np = ((n & 7) << 4) + (n >> 3);  // inverse of perm(n')=(n'&15)*8+(n'>>4)
        WT[which * 128 * 128 + np * 128 + k] = __float2half(W[i]);
    }
}

// ---- scaled 256B-row accumulate: acc[0..15] += s * row -------------------
__device__ __forceinline__ void accs(uint4 ua, uint4 ub, float s, float* acc) {
    union { uint4 u; __half2 h2[4]; } va, vb;
    va.u = ua; vb.u = ub;
#pragma unroll
    for (int q = 0; q < 4; ++q) {
        float2 wa = __half22float2(va.h2[q]);
        float2 wb = __half22float2(vb.h2[q]);
        acc[2 * q]     += s * wa.x;
        acc[2 * q + 1] += s * wa.y;
        acc[8 + 2 * q]     += s * wb.x;
        acc[8 + 2 * q + 1] += s * wb.y;
    }
}

// ====== fused layer: t = 2*p_r + sum p_src  ->  p_next = relu(dv*(dv*tW+b))
// Linearity: agg(h W) == agg(h) W, with p = dinv (.) h pre-scaled, so the
// gather reads fully-materialized data and the GEMM fuses behind it —
// no intra-layer global dependency. SC=true (layer 0): p = x_fp16, scale
// each source row by dinv[src] on the fly.
// 32 nodes/block, 8 lanes/node (2x uint4 = full 256B row per edge).
template <bool SC>
__global__ __launch_bounds__(256, 2) void k_fused(
    const __half* __restrict__ pin, const __half* __restrict__ WTl,
    const float* __restrict__ dinv, const unsigned* __restrict__ packed,
    const unsigned short* __restrict__ eidx, const float* __restrict__ bias,
    __half* __restrict__ pout) {
    __shared__ __half tl[32 * 136];  // +8 pad: conflict-free b128 r/w
    const int t = threadIdx.x;
    const int node8 = t >> 3;  // 0..31
    const int l8 = t & 7;
    const int r = blockIdx.x * 32 + node8;
    const bool valid = r < N_NODES;

    float acc[16];
#pragma unroll
    for (int j = 0; j < 16; ++j) acc[j] = 0.f;
    int i = 0, end = 0;
    if (valid) {
        const uint4* rp = (const uint4*)&pin[(size_t)r * 128];
        uint4 sa = rp[l8], sb = rp[8 + l8];
        float s2 = SC ? 2.f * dinv[r] : 2.f;
        accs(sa, sb, s2, acc);
        unsigned pk = packed[r];
        i = (int)(pk >> 11);
        end = i + (int)(pk & 2047u);
    }
    // 8-edge batches: 16 uint4 (+8 dinv) loads in flight per lane
    for (; i + 8 <= end; i += 8) {
        int my = (int)__builtin_nontemporal_load(&eidx[i + l8]);
        uint4 va[8], vb[8];
        float ds8[8];
#pragma unroll
        for (int j = 0; j < 8; ++j) {
            int s0 = __shfl(my, j, 8);
            const uint4* q = (const uint4*)&pin[(size_t)s0 * 128];
            va[j] = q[l8];
            vb[j] = q[8 + l8];
            if (SC) ds8[j] = dinv[s0];
        }
#pragma unroll
        for (int j = 0; j < 8; ++j)
            accs(va[j], vb[j], SC ? ds8[j] : 1.f, acc);
    }
    if (i < end) {
        int n = end - i;
        int my = (l8 < n) ? (int)eidx[i + l8] : 0;
        for (int j = 0; j < n; ++j) {
            int s0 = __shfl(my, j, 8);
            const uint4* q = (const uint4*)&pin[(size_t)s0 * 128];
            accs(q[l8], q[8 + l8], SC ? dinv[s0] : 1.f, acc);
        }
    }
    // t -> LDS (fp16), two 16B writes; bank pattern is exactly min-cycles
    {
        union { uintx4 u; __half h[8]; } pa, pb;
#pragma unroll
        for (int j = 0; j < 8; ++j) {
            pa.h[j] = __float2half(acc[j]);
            pb.h[j] = __float2half(acc[8 + j]);
        }
        *(uintx4*)&tl[node8 * 136 + 8 * l8] = pa.u;
        *(uintx4*)&tl[node8 * 136 + 64 + 8 * l8] = pb.u;
    }
    __syncthreads();

    // MFMA: 4 waves = 2 row-tiles x 2 col-tiles; 16 mfma each
    const int wave = t >> 6;
    const int lane = t & 63;
    const int m = lane & 15;
    const int quad = lane >> 4;
    const int rtile = wave >> 1;
    const int ctile = wave & 1;
    floatx4 a4[4] = {};
#pragma unroll
    for (int kb = 0; kb < 4; ++kb) {
        half8 af = *(const half8*)&tl[(rtile * 16 + m) * 136 + quad * 8 + kb * 32];
#pragma unroll
        for (int j = 0; j < 4; ++j) {
            half8 bf = *(const half8*)&WTl[(size_t)(((ctile * 4 + j) * 16 + m)) * 128 +
                                           kb * 32 + quad * 8];
            a4[j] = __builtin_amdgcn_mfma_f32_16x16x32_f16(af, bf, a4[j], 0, 0, 0);
        }
    }
    // feature f = 8m + ctile*4 + j ; node = base + rtile*16 + quad*4 + rr
    const int f0 = 8 * m + ctile * 4;
    const float4 bi = *(const float4*)&bias[f0];
    const int nb0 = blockIdx.x * 32 + rtile * 16 + quad * 4;
#pragma unroll
    for (int rr = 0; rr < 4; ++rr) {
        int node = nb0 + rr;
        if (node < N_NODES) {
            float dv = dinv[node];
            union { ushort4 u; __half h[4]; } pk4;
            pk4.h[0] = __float2half(fmaxf(dv * (dv * a4[0][rr] + bi.x), 0.f));
            pk4.h[1] = __float2half(fmaxf(dv * (dv * a4[1][rr] + bi.y), 0.f));
            pk4.h[2] = __float2half(fmaxf(dv * (dv * a4[2][rr] + bi.z), 0.f));
            pk4.h[3] = __float2half(fmaxf(dv * (dv * a4[3][rr] + bi.w), 0.f));
            *(ushort4*)&pout[(size_t)node * 128 + f0] = pk4.u;
        }
    }
}

// ---- dense transform, F_out = 16 (last layer): p3 fp16 in, fp32 out -------
// input is pre-scaled p3 = dinv (.) h3, so (p3 W3) == dinv (.) (h3 W3): no
// dinv multiply here; gather4 consumes it unchanged.
__global__ __launch_bounds__(256) void k_gemm16(const __half* __restrict__ in,
                                                const float* __restrict__ W,
                                                float* __restrict__ hs) {
    __shared__ float Wt[16 * 132];
    const int tid = threadIdx.x;
    for (int i = tid; i < 128 * 16; i += 256) {
        int k = i >> 4, c = i & 15;
        Wt[c * 132 + k] = W[i];
    }
    __syncthreads();
    int gid = blockIdx.x * 256 + tid;  // grid exactly 50000*16
    int r = gid >> 4, c = gid & 15;
    const __half* arow = &in[(size_t)r * 128];
    const float* wrow = &Wt[c * 132];
    float acc = 0.f;
#pragma unroll
    for (int k0 = 0; k0 < 128; k0 += 8) {
        union { uint4 u; __half2 h2[4]; } p;
        p.u = *(const uint4*)&arow[k0];
#pragma unroll
        for (int q = 0; q < 4; ++q) {
            float2 a = __half22float2(p.h2[q]);
            acc += a.x * wrow[k0 + 2 * q] + a.y * wrow[k0 + 2 * q + 1];
        }
    }
    hs[gid] = acc;
}

// ====== fp32 gather for the last (F=16) layer ======
__global__ __launch_bounds__(256) void k_gather4(const unsigned* __restrict__ packed,
                                                 const unsigned short* __restrict__ eidx,
                                                 const float* __restrict__ hs,
                                                 const float* __restrict__ dinv,
                                                 const float* __restrict__ bias,
                                                 float* __restrict__ out) {
    int tid = blockIdx.x * 256 + threadIdx.x;
    int r = tid >> 2;
    if (r >= N_NODES) return;
    int l = tid & 3;
    int f = l * 4;
    const float dv = dinv[r];
    const float4 bi = *(const float4*)&bias[f];
    float4 h = *(const float4*)&hs[(size_t)r * 16 + f];
    float ax = 2.f * h.x, ay = 2.f * h.y, az = 2.f * h.z, aw = 2.f * h.w;
    unsigned pk = packed[r];
    int i = (int)(pk >> 11);
    int end = i + (int)(pk & 2047u);
    for (; i + 4 <= end; i += 4) {
        int my = (int)eidx[i + l];
#pragma unroll
        for (int j = 0; j < 4; ++j) {
            int s = __shfl(my, j, 4);
            float4 v = *(const float4*)&hs[(size_t)s * 16 + f];
            ax += v.x; ay += v.y; az += v.z; aw += v.w;
        }
    }
    if (i < end) {
        int n = end - i;
        int my = (l < n) ? (int)eidx[i + l] : 0;
        for (int j = 0; j < n; ++j) {
            int s = __shfl(my, j, 4);
            float4 v = *(const float4*)&hs[(size_t)s * 16 + f];
            ax += v.x; ay += v.y; az += v.z; aw += v.w;
        }
    }
    float v0 = tanhf(dv * ax + bi.x);
    float v1 = tanhf(dv * ay + bi.y);
    float v2 = tanhf(dv * az + bi.z);
    float v3 = tanhf(dv * aw + bi.w);
    floatx4 o = {v0, v1, v2, v3};
    __builtin_nontemporal_store(o, (floatx4*)&out[(size_t)r * 16 + f]);
}

extern "C" void kernel_launch(void* const* d_in, const int* in_sizes, int n_in,
                              void* d_out, int out_size, void* d_ws, size_t ws_size,
                              hipStream_t stream) {
    const float* x  = (const float*)d_in[0];
    const int* ei   = (const int*)d_in[1];
    const float* W0 = (const float*)d_in[2];
    const float* b0 = (const float*)d_in[3];
    const float* W1 = (const float*)d_in[4];
    const float* b1 = (const float*)d_in[5];
    const float* W2 = (const float*)d_in[6];
    const float* b2 = (const float*)d_in[7];
    const float* W3 = (const float*)d_in[8];
    const float* b3 = (const float*)d_in[9];
    const int* src = ei;
    const int* dst = ei + N_EDGES;

    // ws layout (16B-aligned):
    __half* A      = (__half*)d_ws;                        // 50000*128 f16 (ping)
    __half* P      = A + (size_t)N_NODES * 128;            // 50000*128 f16 (pong)
    __half* WT     = P + (size_t)N_NODES * 128;            // 3*128*128 f16
    float*  H16    = (float*)(WT + 3 * 128 * 128);         // 50000*16 f32
    float*  dinv   = H16 + (size_t)N_NODES * 16;           // 50000
    unsigned* packed = (unsigned*)(dinv + N_NODES);        // 50000
    int*    gcur   = (int*)(packed + N_NODES);             // 1024 (NB padded)
    unsigned short* eidx = (unsigned short*)(gcur + 1024); // NB*CAP u16
    unsigned* arena = (unsigned*)(eidx + NB * CAP);        // NB*CAP

    // ---- CSR build + prep (every call; ws is re-poisoned) ----
    (void)hipMemsetAsync(gcur, 0, 1024 * sizeof(int), stream);
    k_bucket<<<BUCKET_BLOCKS, 256, 0, stream>>>(src, dst, gcur, arena);
    k_fill3prep<<<FILL_GRID, 256, 0, stream>>>(arena, gcur, packed, dinv,
                                               eidx, x, A, W0, W1, W2, WT);

    // ---- fused layers: gather(p) -> MFMA -> p_next, ping-pong A/P ----
    k_fused<true><<<FB, 256, 0, stream>>>(A, WT, dinv, packed, eidx, b0, P);
    k_fused<false><<<FB, 256, 0, stream>>>(P, WT + 128 * 128, dinv, packed,
                                           eidx, b1, A);
    k_fused<false><<<FB, 256, 0, stream>>>(A, WT + 2 * 128 * 128, dinv, packed,
                                           eidx, b2, P);
    // ---- layer 3 (128 -> 16, tanh): gemm-first, 16-wide gather ----
    k_gemm16<<<N_NODES * 16 / 256, 256, 0, stream>>>(P, W3, H16);
    k_gather4<<<(N_NODES * 4 + 255) / 256, 256, 0, stream>>>(
        packed, eidx, H16, dinv, b3, (float*)d_out);
}